// Round 8
// baseline (318.722 us; speedup 1.0000x reference)
//
#include <hip/hip_runtime.h>
#include <math.h>

#define G      32
#define NCELLS (G * G * G)        // 32768
#define LOF    (-6.0f)
#define HH     0.375f             // 12/32
#define INVH   (1.0f / 0.375f)
#define SPLIT  8                  // sub-threads per query
#define DELTA  1e-3f              // prune slack >> fp d2 rounding (~3e-5)

__device__ __forceinline__ int cell_coord(float x) {
    int c = (int)floorf((x - LOF) * INVH);
    c = c < 0 ? 0 : c;
    return c > G - 1 ? G - 1 : c;
}
__device__ __forceinline__ int imax2(int a, int b) { return a > b ? a : b; }
__device__ __forceinline__ int imin2(int a, int b) { return a < b ? a : b; }
__device__ __forceinline__ int iabs(int a) { return a < 0 ? -a : a; }

// lexicographic (d, idx) 3-slot insert == jax top_k tie semantics (order-free)
#define LEXINSERT(dv, jv) do {                                        \
    float d_ = (dv); int j_ = (jv);                                   \
    bool l0 = (d_ < e0) || ((d_ == e0) && (j_ < i0));                 \
    bool l1 = (d_ < e1) || ((d_ == e1) && (j_ < i1));                 \
    bool l2 = (d_ < e2) || ((d_ == e2) && (j_ < i2));                 \
    int   ni0 = l0 ? j_ : i0;                                         \
    int   ni1 = l0 ? i0 : (l1 ? j_ : i1);                             \
    int   ni2 = l1 ? i1 : (l2 ? j_ : i2);                             \
    float ne0 = l0 ? d_ : e0;                                         \
    float ne1 = l0 ? e0 : (l1 ? d_ : e1);                             \
    float ne2 = l1 ? e1 : (l2 ? d_ : e2);                             \
    e0 = ne0; e1 = ne1; e2 = ne2; i0 = ni0; i1 = ni1; i2 = ni2;       \
} while (0)

__global__ __launch_bounds__(256) void zero_ints(int* __restrict__ p, int n) {
    int i = blockIdx.x * 256 + threadIdx.x;
    if (i < n) p[i] = 0;
}

__global__ __launch_bounds__(256) void bin_count(
    const float* __restrict__ ref, int* __restrict__ cnt, int Nr) {
    int j = blockIdx.x * 256 + threadIdx.x;
    if (j >= Nr) return;
    int cx = cell_coord(ref[3 * j + 0]);
    int cy = cell_coord(ref[3 * j + 1]);
    int cz = cell_coord(ref[3 * j + 2]);
    atomicAdd(&cnt[(cz * G + cy) * G + cx], 1);
}

// single-block exclusive scan over NCELLS = 1024 threads * 32 cells each
__global__ __launch_bounds__(1024) void scan_cells(
    const int* __restrict__ cnt, int* __restrict__ off, int* __restrict__ cur) {
    __shared__ int wsum[16];
    int tid = threadIdx.x, lane = tid & 63, wid = tid >> 6;
    int base = tid * 32;
    int local[32];
    int s = 0;
#pragma unroll
    for (int k = 0; k < 32; ++k) { local[k] = cnt[base + k]; s += local[k]; }
    int incl = s;
#pragma unroll
    for (int sh = 1; sh < 64; sh <<= 1) {
        int t = __shfl_up(incl, sh, 64);
        if (lane >= sh) incl += t;
    }
    if (lane == 63) wsum[wid] = incl;
    __syncthreads();
    if (wid == 0) {
        int w = (lane < 16) ? wsum[lane] : 0;
        int wincl = w;
#pragma unroll
        for (int sh = 1; sh < 16; sh <<= 1) {
            int t = __shfl_up(wincl, sh, 64);
            if (lane >= sh) wincl += t;
        }
        if (lane < 16) wsum[lane] = wincl - w;   // exclusive wave offset
    }
    __syncthreads();
    int run = wsum[wid] + incl - s;              // exclusive prefix
#pragma unroll
    for (int k = 0; k < 32; ++k) {
        off[base + k] = run;
        cur[base + k] = run;
        run += local[k];
    }
    if (tid == 1023) off[NCELLS] = run;
}

// scatter refs: sorted float4 (x,y,z, idx-as-bits); r2 recomputed at use
__global__ __launch_bounds__(256) void bin_fill(
    const float* __restrict__ ref, int* __restrict__ cur,
    float4* __restrict__ srt, int Nr) {
    int j = blockIdx.x * 256 + threadIdx.x;
    if (j >= Nr) return;
    float x = ref[3 * j + 0], y = ref[3 * j + 1], z = ref[3 * j + 2];
    int cx = cell_coord(x), cy = cell_coord(y), cz = cell_coord(z);
    int cell = (cz * G + cy) * G + cx;
    int pos = atomicAdd(&cur[cell], 1);
    srt[pos] = make_float4(x, y, z, __int_as_float(j));
}

// ---------------------------------------------------------------------------
// Grid kNN + finish, fused. 8 sub-threads per query (lanes 8q..8q+7 of the
// wave group). Ring expansion with exact conservative prune:
//   lb(m) = max(0, (m-1)*H + fmin_face), prune if lb^2 > group_e2 + DELTA.
// group_e2 = shfl-min of private e2 (>= true e2 -> conservative). e2=INF
// until a sub-thread holds 3 candidates -> never stops before >=3 found.
// d2 chain bit-identical to the passing brute-force kernels; clamp after
// scan; lexicographic (d, idx) everywhere == jax top_k tie semantics.
// ---------------------------------------------------------------------------
__global__ __launch_bounds__(256) void knn_grid(
    const float* __restrict__ qpts, const float4* __restrict__ srt,
    const int* __restrict__ off, const float* __restrict__ flow,
    float* __restrict__ out, int Nq) {
#pragma clang fp contract(off)
    int tid  = blockIdx.x * 256 + threadIdx.x;
    int lane = threadIdx.x & 63;
    int sub  = lane & (SPLIT - 1);
    int q    = tid >> 3;                  // SPLIT = 8
    bool valid = q < Nq;

    float qx = 0.f, qy = 0.f, qz = 0.f;
    if (valid) { qx = qpts[3 * q]; qy = qpts[3 * q + 1]; qz = qpts[3 * q + 2]; }
    float q2 = (qx * qx + qy * qy) + qz * qz;

    int cx = cell_coord(qx), cy = cell_coord(qy), cz = cell_coord(qz);
    float bx = LOF + cx * HH, by = LOF + cy * HH, bz = LOF + cz * HH;
    float fmin = qx - bx;                      // signed face distances
    fmin = fminf(fmin, (bx + HH) - qx);
    fmin = fminf(fmin, qy - by);
    fmin = fminf(fmin, (by + HH) - qy);
    fmin = fminf(fmin, qz - bz);
    fmin = fminf(fmin, (bz + HH) - qz);

    const float FINF = __builtin_inff();
    float e0 = FINF, e1 = FINF, e2 = FINF;
    int   i0 = 0x7fffffff, i1 = 0x7fffffff, i2 = 0x7fffffff;

    for (int m = 0; m < G; ++m) {
        if (m > 0) {
            float ge = e2;                     // group-min e2 (conservative)
            ge = fminf(ge, __shfl_xor(ge, 1, 64));
            ge = fminf(ge, __shfl_xor(ge, 2, 64));
            ge = fminf(ge, __shfl_xor(ge, 4, 64));
            float lb = (float)(m - 1) * HH + fmin;
            lb = fmaxf(lb, 0.0f);
            if (lb * lb > ge + DELTA) break;   // group-uniform break
        }
        int zlo = imax2(cz - m, 0), zhi = imin2(cz + m, G - 1);
        int ylo = imax2(cy - m, 0), yhi = imin2(cy + m, G - 1);
        int xlo = imax2(cx - m, 0), xhi = imin2(cx + m, G - 1);
        for (int z = zlo; z <= zhi; ++z) {
            int az = iabs(z - cz);
            for (int y = ylo; y <= yhi; ++y) {
                int am = imax2(az, iabs(y - cy));
                for (int x = xlo; x <= xhi; ++x) {
                    int ch = imax2(am, iabs(x - cx));
                    if (ch != m) continue;     // shell-m cells only
                    int cell = (z * G + y) * G + x;
                    int cs = off[cell], ce = off[cell + 1];
                    for (int u = cs + sub; u < ce; u += SPLIT) {
                        float4 r = srt[u];
                        float r2 = (r.x * r.x + r.y * r.y) + r.z * r.z;
                        float td = qx * r.x;
                        td = fmaf(qy, r.y, td);
                        td = fmaf(qz, r.z, td);
                        float a = q2 + r2;
                        float d = fmaf(-2.0f, td, a);   // unclamped d2
                        int jj = __float_as_int(r.w);
                        LEXINSERT(d, jj);
                    }
                }
            }
        }
    }

    // clamp survivors (reference: max(d2,0) before ranking/sqrt)
    e0 = fmaxf(e0, 0.0f);
    e1 = fmaxf(e1, 0.0f);
    e2 = fmaxf(e2, 0.0f);

    // merge the 8 sub-thread top-3 sets (lex-correct, R4-proven pattern)
#pragma unroll
    for (int mk = 1; mk < SPLIT; mk <<= 1) {
        float f0 = __shfl_xor(e0, mk, 64);
        float f1 = __shfl_xor(e1, mk, 64);
        float f2 = __shfl_xor(e2, mk, 64);
        int   g0 = __shfl_xor(i0, mk, 64);
        int   g1 = __shfl_xor(i1, mk, 64);
        int   g2 = __shfl_xor(i2, mk, 64);
        LEXINSERT(f0, g0);
        LEXINSERT(f1, g1);
        LEXINSERT(f2, g2);
    }

    if (valid && sub == 0) {
        float s0 = sqrtf(e0);
        float s1 = sqrtf(e1);
        float s2 = sqrtf(e2);
        float w0 = 1.0f / (s0 + 1e-8f);
        float w1 = 1.0f / (s1 + 1e-8f);
        float w2 = 1.0f / (s2 + 1e-8f);
        float wsum = (w0 + w1) + w2;
        w0 = w0 / wsum;
        w1 = w1 / wsum;
        w2 = w2 / wsum;

        float f0x = flow[i0 * 3 + 0], f0y = flow[i0 * 3 + 1], f0z = flow[i0 * 3 + 2];
        float f1x = flow[i1 * 3 + 0], f1y = flow[i1 * 3 + 1], f1z = flow[i1 * 3 + 2];
        float f2x = flow[i2 * 3 + 0], f2y = flow[i2 * 3 + 1], f2z = flow[i2 * 3 + 2];

        out[q * 3 + 0] = (w0 * f0x + w1 * f1x) + w2 * f2x;
        out[q * 3 + 1] = (w0 * f0y + w1 * f1y) + w2 * f2y;
        out[q * 3 + 2] = (w0 * f0z + w1 * f1z) + w2 * f2z;
    }
}

extern "C" void kernel_launch(void* const* d_in, const int* in_sizes, int n_in,
                              void* d_out, int out_size, void* d_ws, size_t ws_size,
                              hipStream_t stream) {
    const float* q    = (const float*)d_in[0];
    const float* ref  = (const float*)d_in[1];
    const float* flow = (const float*)d_in[2];
    float* out = (float*)d_out;

    int Nq = in_sizes[0] / 3;
    int Nr = in_sizes[1] / 3;

    char* ws = (char*)d_ws;
    float4* srt = (float4*)ws;                       // Nr float4 (16B aligned)
    size_t o = (size_t)Nr * sizeof(float4);
    int* off = (int*)(ws + o);  o += (size_t)(NCELLS + 1) * sizeof(int);
    int* cur = (int*)(ws + o);  o += (size_t)NCELLS * sizeof(int);
    int* cnt = (int*)(ws + o);  o += (size_t)NCELLS * sizeof(int);

    zero_ints<<<(NCELLS + 255) / 256, 256, 0, stream>>>(cnt, NCELLS);
    bin_count<<<(Nr + 255) / 256, 256, 0, stream>>>(ref, cnt, Nr);
    scan_cells<<<1, 1024, 0, stream>>>(cnt, off, cur);
    bin_fill<<<(Nr + 255) / 256, 256, 0, stream>>>(ref, cur, srt, Nr);

    int threads = Nq * SPLIT;
    knn_grid<<<(threads + 255) / 256, 256, 0, stream>>>(
        q, srt, off, flow, out, Nq);
}

// Round 9
// 127.718 us; speedup vs baseline: 2.4955x; 2.4955x over previous
//
#include <hip/hip_runtime.h>
#include <math.h>

#define G      32
#define NCELLS (G * G * G)        // 32768
#define LOF    (-6.0f)
#define HH     0.375f             // 12/32
#define INVH   (1.0f / 0.375f)
#define DELTA  1e-3f              // prune slack >> fp d2 rounding (~3e-5)

__device__ __forceinline__ int cell_coord(float x) {
    int c = (int)floorf((x - LOF) * INVH);
    c = c < 0 ? 0 : c;
    return c > G - 1 ? G - 1 : c;
}
__device__ __forceinline__ int imax2(int a, int b) { return a > b ? a : b; }
__device__ __forceinline__ int imin2(int a, int b) { return a < b ? a : b; }
__device__ __forceinline__ int iabs(int a) { return a < 0 ? -a : a; }
__device__ __forceinline__ float rdfl(float v) {
    return __int_as_float(__builtin_amdgcn_readfirstlane(__float_as_int(v)));
}

// lexicographic (d, idx) 3-slot insert == jax top_k tie semantics (order-free)
#define LEXINSERT(dv, jv) do {                                        \
    float d_ = (dv); int j_ = (jv);                                   \
    bool l0 = (d_ < e0) || ((d_ == e0) && (j_ < i0));                 \
    bool l1 = (d_ < e1) || ((d_ == e1) && (j_ < i1));                 \
    bool l2 = (d_ < e2) || ((d_ == e2) && (j_ < i2));                 \
    int   ni0 = l0 ? j_ : i0;                                         \
    int   ni1 = l0 ? i0 : (l1 ? j_ : i1);                             \
    int   ni2 = l1 ? i1 : (l2 ? j_ : i2);                             \
    float ne0 = l0 ? d_ : e0;                                         \
    float ne1 = l0 ? e0 : (l1 ? d_ : e1);                             \
    float ne2 = l1 ? e1 : (l2 ? d_ : e2);                             \
    e0 = ne0; e1 = ne1; e2 = ne2; i0 = ni0; i1 = ni1; i2 = ni2;       \
} while (0)

// lanes split refs [lo,hi) of a contiguous run; coalesced float4 loads.
// d2 chain bit-identical to the passing kernels (contract off in caller).
#define SCAN_RUN(lo_, hi_) do {                                       \
    for (int u = (lo_) + lane; u < (hi_); u += 64) {                  \
        float4 rr = srt[u];                                           \
        float xx = rr.x * rr.x;                                       \
        float yy = rr.y * rr.y;                                       \
        float zz = rr.z * rr.z;                                       \
        float r2 = (xx + yy) + zz;                                    \
        float td = qx * rr.x;                                         \
        td = fmaf(qy, rr.y, td);                                      \
        td = fmaf(qz, rr.z, td);                                      \
        float aa = q2 + r2;                                           \
        float dd = fmaf(-2.0f, td, aa);                               \
        int jj = __float_as_int(rr.w);                                \
        LEXINSERT(dd, jj);                                            \
    }                                                                 \
} while (0)

__global__ __launch_bounds__(256) void zero_ints(int* __restrict__ p, int n) {
    int i = blockIdx.x * 256 + threadIdx.x;
    if (i < n) p[i] = 0;
}

__global__ __launch_bounds__(256) void bin_count(
    const float* __restrict__ ref, int* __restrict__ cnt, int Nr) {
    int j = blockIdx.x * 256 + threadIdx.x;
    if (j >= Nr) return;
    int cx = cell_coord(ref[3 * j + 0]);
    int cy = cell_coord(ref[3 * j + 1]);
    int cz = cell_coord(ref[3 * j + 2]);
    atomicAdd(&cnt[(cz * G + cy) * G + cx], 1);
}

// single-block exclusive scan over NCELLS = 1024 threads * 32 cells each
__global__ __launch_bounds__(1024) void scan_cells(
    const int* __restrict__ cnt, int* __restrict__ off, int* __restrict__ cur) {
    __shared__ int wsum[16];
    int tid = threadIdx.x, lane = tid & 63, wid = tid >> 6;
    int base = tid * 32;
    int local[32];
    int s = 0;
#pragma unroll
    for (int k = 0; k < 32; ++k) { local[k] = cnt[base + k]; s += local[k]; }
    int incl = s;
#pragma unroll
    for (int sh = 1; sh < 64; sh <<= 1) {
        int t = __shfl_up(incl, sh, 64);
        if (lane >= sh) incl += t;
    }
    if (lane == 63) wsum[wid] = incl;
    __syncthreads();
    if (wid == 0) {
        int w = (lane < 16) ? wsum[lane] : 0;
        int wincl = w;
#pragma unroll
        for (int sh = 1; sh < 16; sh <<= 1) {
            int t = __shfl_up(wincl, sh, 64);
            if (lane >= sh) wincl += t;
        }
        if (lane < 16) wsum[lane] = wincl - w;   // exclusive wave offset
    }
    __syncthreads();
    int run = wsum[wid] + incl - s;              // exclusive prefix
#pragma unroll
    for (int k = 0; k < 32; ++k) {
        off[base + k] = run;
        cur[base + k] = run;
        run += local[k];
    }
    if (tid == 1023) off[NCELLS] = run;
}

// scatter refs: sorted float4 (x,y,z, idx-as-bits); r2 recomputed at use
__global__ __launch_bounds__(256) void bin_fill(
    const float* __restrict__ ref, int* __restrict__ cur,
    float4* __restrict__ srt, int Nr) {
    int j = blockIdx.x * 256 + threadIdx.x;
    if (j >= Nr) return;
    float x = ref[3 * j + 0], y = ref[3 * j + 1], z = ref[3 * j + 2];
    int cx = cell_coord(x), cy = cell_coord(y), cz = cell_coord(z);
    int cell = (cz * G + cy) * G + cx;
    int pos = atomicAdd(&cur[cell], 1);
    srt[pos] = make_float4(x, y, z, __int_as_float(j));
}

// ---------------------------------------------------------------------------
// Grid kNN + finish: ONE WAVE PER QUERY. Query + cell walk are wave-uniform
// (readfirstlane -> SGPRs, off[] via scalar loads, uniform branches); the 64
// lanes split each contiguous ref-run with coalesced loads. Ring enumeration
// is face/edge-exact (no O(M^4) box rescan): per (z,y) row, face rows are one
// contiguous srt run, non-face rows are two single cells. Prune: wave-min e2
// (conservative >= true e2), lb = max(0,(m-1)H + fmin), stop when
// lb^2 > ge + DELTA. e2 stays INF until a lane holds 3 -> never premature.
// ---------------------------------------------------------------------------
__global__ __launch_bounds__(256) void knn_grid(
    const float* __restrict__ qpts, const float4* __restrict__ srt,
    const int* __restrict__ off, const float* __restrict__ flow,
    float* __restrict__ out, int Nq) {
#pragma clang fp contract(off)
    int lane = threadIdx.x & 63;
    int q = blockIdx.x * 4 + (threadIdx.x >> 6);   // one wave per query
    if (q >= Nq) return;

    float qx = rdfl(qpts[3 * q + 0]);
    float qy = rdfl(qpts[3 * q + 1]);
    float qz = rdfl(qpts[3 * q + 2]);
    float q2 = (qx * qx + qy * qy) + qz * qz;

    int cx = cell_coord(qx), cy = cell_coord(qy), cz = cell_coord(qz);
    float bx = LOF + cx * HH, by = LOF + cy * HH, bz = LOF + cz * HH;
    float fmin = qx - bx;                      // signed face distances
    fmin = fminf(fmin, (bx + HH) - qx);
    fmin = fminf(fmin, qy - by);
    fmin = fminf(fmin, (by + HH) - qy);
    fmin = fminf(fmin, qz - bz);
    fmin = fminf(fmin, (bz + HH) - qz);

    const float FINF = __builtin_inff();
    float e0 = FINF, e1 = FINF, e2 = FINF;
    int   i0 = 0x7fffffff, i1 = 0x7fffffff, i2 = 0x7fffffff;

    for (int m = 0; m < G; ++m) {
        if (m > 0) {
            float ge = e2;                     // wave-min e2 (conservative)
#pragma unroll
            for (int mk = 1; mk < 64; mk <<= 1)
                ge = fminf(ge, __shfl_xor(ge, mk, 64));
            ge = rdfl(ge);
            float lb = fmaxf((float)(m - 1) * HH + fmin, 0.0f);
            if (lb * lb > ge + DELTA) break;   // wave-uniform break
        }
        if (m == 0) {
            int cell = (cz * G + cy) * G + cx;
            int lo = off[cell], hi = off[cell + 1];
            SCAN_RUN(lo, hi);
        } else {
            int zlo = imax2(cz - m, 0), zhi = imin2(cz + m, G - 1);
            int ylo = imax2(cy - m, 0), yhi = imin2(cy + m, G - 1);
            int xlo = imax2(cx - m, 0), xhi = imin2(cx + m, G - 1);
            for (int z = zlo; z <= zhi; ++z) {
                int fz = (iabs(z - cz) == m);
                for (int y = ylo; y <= yhi; ++y) {
                    int face = fz | (iabs(y - cy) == m);
                    int rowbase = (z * G + y) * G;
                    if (face) {                 // contiguous run of cells
                        int lo = off[rowbase + xlo];
                        int hi = off[rowbase + xhi + 1];
                        SCAN_RUN(lo, hi);
                    } else {                    // only x = cx +- m
                        if (cx - m >= 0) {
                            int cell = rowbase + (cx - m);
                            int lo = off[cell], hi = off[cell + 1];
                            SCAN_RUN(lo, hi);
                        }
                        if (cx + m <= G - 1) {
                            int cell = rowbase + (cx + m);
                            int lo = off[cell], hi = off[cell + 1];
                            SCAN_RUN(lo, hi);
                        }
                    }
                }
            }
        }
    }

    // clamp survivors (reference: max(d2,0) before ranking/sqrt)
    e0 = fmaxf(e0, 0.0f);
    e1 = fmaxf(e1, 0.0f);
    e2 = fmaxf(e2, 0.0f);

    // 64-lane butterfly lex-merge (disjoint sets at every stage -> no dups)
#pragma unroll
    for (int mk = 1; mk < 64; mk <<= 1) {
        float f0 = __shfl_xor(e0, mk, 64);
        float f1 = __shfl_xor(e1, mk, 64);
        float f2 = __shfl_xor(e2, mk, 64);
        int   g0 = __shfl_xor(i0, mk, 64);
        int   g1 = __shfl_xor(i1, mk, 64);
        int   g2 = __shfl_xor(i2, mk, 64);
        LEXINSERT(f0, g0);
        LEXINSERT(f1, g1);
        LEXINSERT(f2, g2);
    }

    if (lane == 0) {
        float s0 = sqrtf(e0);
        float s1 = sqrtf(e1);
        float s2 = sqrtf(e2);
        float w0 = 1.0f / (s0 + 1e-8f);
        float w1 = 1.0f / (s1 + 1e-8f);
        float w2 = 1.0f / (s2 + 1e-8f);
        float wsum = (w0 + w1) + w2;
        w0 = w0 / wsum;
        w1 = w1 / wsum;
        w2 = w2 / wsum;

        float f0x = flow[i0 * 3 + 0], f0y = flow[i0 * 3 + 1], f0z = flow[i0 * 3 + 2];
        float f1x = flow[i1 * 3 + 0], f1y = flow[i1 * 3 + 1], f1z = flow[i1 * 3 + 2];
        float f2x = flow[i2 * 3 + 0], f2y = flow[i2 * 3 + 1], f2z = flow[i2 * 3 + 2];

        out[q * 3 + 0] = (w0 * f0x + w1 * f1x) + w2 * f2x;
        out[q * 3 + 1] = (w0 * f0y + w1 * f1y) + w2 * f2y;
        out[q * 3 + 2] = (w0 * f0z + w1 * f1z) + w2 * f2z;
    }
}

extern "C" void kernel_launch(void* const* d_in, const int* in_sizes, int n_in,
                              void* d_out, int out_size, void* d_ws, size_t ws_size,
                              hipStream_t stream) {
    const float* q    = (const float*)d_in[0];
    const float* ref  = (const float*)d_in[1];
    const float* flow = (const float*)d_in[2];
    float* out = (float*)d_out;

    int Nq = in_sizes[0] / 3;
    int Nr = in_sizes[1] / 3;

    char* ws = (char*)d_ws;
    float4* srt = (float4*)ws;                       // Nr float4 (16B aligned)
    size_t o = (size_t)Nr * sizeof(float4);
    int* off = (int*)(ws + o);  o += (size_t)(NCELLS + 1) * sizeof(int);
    int* cur = (int*)(ws + o);  o += (size_t)NCELLS * sizeof(int);
    int* cnt = (int*)(ws + o);  o += (size_t)NCELLS * sizeof(int);

    zero_ints<<<(NCELLS + 255) / 256, 256, 0, stream>>>(cnt, NCELLS);
    bin_count<<<(Nr + 255) / 256, 256, 0, stream>>>(ref, cnt, Nr);
    scan_cells<<<1, 1024, 0, stream>>>(cnt, off, cur);
    bin_fill<<<(Nr + 255) / 256, 256, 0, stream>>>(ref, cur, srt, Nr);

    int nBlocks = (Nq + 3) / 4;                      // 4 waves (queries)/block
    knn_grid<<<nBlocks, 256, 0, stream>>>(q, srt, off, flow, out, Nq);
}